// Round 14
// baseline (85.180 us; speedup 1.0000x reference)
//
#include <hip/hip_runtime.h>
#include <cstdint>
#include <cstddef>

#define DEV static __device__ __forceinline__

typedef __bf16 bf16x8 __attribute__((ext_vector_type(8)));
typedef __bf16 bf16x4 __attribute__((ext_vector_type(4)));
typedef float  f32x4  __attribute__((ext_vector_type(4)));
typedef unsigned short us4 __attribute__((ext_vector_type(4)));
typedef unsigned int   u32x4 __attribute__((ext_vector_type(4)));

DEV unsigned short f2bf(float f) {
  unsigned u = __float_as_uint(f);
  u += 0x7FFFu + ((u >> 16) & 1u);          // round-to-nearest-even
  return (unsigned short)(u >> 16);
}

// fixed problem dims
constexpr int   Bn = 4, Nn = 4096, Cn = 256, HEADSn = 8, DHn = 32, NKn = 1024;
constexpr float SCALEc = 0.17677669529663689f;   // 1/sqrt(32)
constexpr float L2E    = 1.4426950408889634f;

// ---------------- f32 -> bf16 convert with optional scale ----------------
__global__ void k_f32_to_bf16(const float* __restrict__ src,
                              unsigned short* __restrict__ dst, int n4, float scale) {
  int i = blockIdx.x * blockDim.x + threadIdx.x;
  if (i < n4) {
    f32x4 v = *(const f32x4*)(src + 4 * (size_t)i);
    us4 o;
    o[0] = f2bf(v[0] * scale); o[1] = f2bf(v[1] * scale);
    o[2] = f2bf(v[2] * scale); o[3] = f2bf(v[3] * scale);
    *(us4*)(dst + 4 * (size_t)i) = o;
  }
}

// ---------------- depthwise 2x2 stride-2 conv + BatchNorm(eval) -> xk bf16 ----------------
__global__ void k_conv_bn(const float* __restrict__ x,
                          const float* __restrict__ srw, const float* __restrict__ srb,
                          const float* __restrict__ bng, const float* __restrict__ bnb,
                          const float* __restrict__ bnm, const float* __restrict__ bnv,
                          unsigned short* __restrict__ xk) {
  const int m = blockIdx.x;           // 0..1023  (i*32+j)
  const int b = blockIdx.y;           // 0..3
  const int c = threadIdx.x;          // 0..255
  const int i = m >> 5, j = m & 31;
  const int n00 = (2 * i) * 64 + 2 * j;
  const size_t base = ((size_t)b * Nn) * Cn + c;
  float w0 = srw[c * 4 + 0], w1 = srw[c * 4 + 1], w2 = srw[c * 4 + 2], w3 = srw[c * 4 + 3];
  float acc = x[base + (size_t)n00 * Cn] * w0
            + x[base + (size_t)(n00 + 1) * Cn] * w1
            + x[base + (size_t)(n00 + 64) * Cn] * w2
            + x[base + (size_t)(n00 + 65) * Cn] * w3
            + srb[c];
  float inv_std = bng[c] * rsqrtf(bnv[c] + 1e-5f);
  acc = (acc - bnm[c]) * inv_std + bnb[c];
  xk[((size_t)b * NKn + m) * Cn + c] = f2bf(acc);
}

// ---------------- LDS-staged bf16 MFMA GEMM: out[m,o] = sum_k A[m,k]*W[o,k] ----------------
template <int MODE>
__global__ __launch_bounds__(256) void k_gemm(const unsigned short* __restrict__ A,
                                              const unsigned short* __restrict__ W,
                                              void* __restrict__ outp,
                                              const float* __restrict__ bias, int rs) {
  __shared__ __align__(16) unsigned short sA[64 * 256];
  __shared__ __align__(16) unsigned short sW[64 * 256];
  const int tid = threadIdx.x;
  const int lane = tid & 63, w = tid >> 6;
  const int g = lane >> 4, c = lane & 15;
  const int m0 = blockIdx.x * 64, o0 = blockIdx.y * 64;

#pragma unroll
  for (int r = 0; r < 8; ++r) {
    const int row = r * 8 + (tid >> 5);
    const int u = tid & 31;                 // 16B unit within 512B row
    const int usw = u ^ (row & 7);
    bf16x8 va = *(const bf16x8*)(A + (size_t)(m0 + row) * Cn + u * 8);
    *(bf16x8*)(sA + row * Cn + usw * 8) = va;
    bf16x8 vw = *(const bf16x8*)(W + (size_t)(o0 + row) * Cn + u * 8);
    *(bf16x8*)(sW + row * Cn + usw * 8) = vw;
  }
  __syncthreads();

  f32x4 acc[4] = {};
  const int rowa = w * 16 + c;
#pragma unroll
  for (int ks = 0; ks < 8; ++ks) {
    bf16x8 af = *(const bf16x8*)(sA + rowa * Cn + ((ks * 4 + g) ^ (c & 7)) * 8);
#pragma unroll
    for (int t = 0; t < 4; ++t) {
      const int roww = 16 * t + c;
      bf16x8 wf = *(const bf16x8*)(sW + roww * Cn + ((ks * 4 + g) ^ (c & 7)) * 8);
      acc[t] = __builtin_amdgcn_mfma_f32_16x16x32_bf16(af, wf, acc[t], 0, 0, 0);
    }
  }

  const int mb = m0 + w * 16;
  if (MODE == 0) {
    unsigned short* ob = (unsigned short*)outp;
#pragma unroll
    for (int t = 0; t < 4; ++t)
#pragma unroll
      for (int r = 0; r < 4; ++r)
        ob[(size_t)(mb + 4 * g + r) * Cn + o0 + 16 * t + c] = f2bf(acc[t][r]);
  } else if (MODE == 1) {
    // v2 layout: [b][h][kvblk32][dv32][g4][j8] shorts
    unsigned short* vt = (unsigned short*)outp;
    const int m4 = mb + 4 * g;
    const int b = m4 >> 10;
    const int kvblk = (m4 & 1023) >> 5;
    const int jh = (m4 >> 4) & 1;
#pragma unroll
    for (int t = 0; t < 4; ++t) {
      const int o = o0 + 16 * t + c;
      const int h = o >> 5, dv = o & 31;
      us4 pk;
      pk[0] = f2bf(acc[t][0]); pk[1] = f2bf(acc[t][1]);
      pk[2] = f2bf(acc[t][2]); pk[3] = f2bf(acc[t][3]);
      *(us4*)(vt + ((size_t)(((b * 8 + h) * 32 + kvblk) * 32 + dv)) * 32 + g * 8 + jh * 4) = pk;
    }
  } else if (MODE == 2) {
    float* of = (float*)outp;
#pragma unroll
    for (int t = 0; t < 4; ++t) {
      const int o = o0 + 16 * t + c;
      const float bv = bias[o];
#pragma unroll
      for (int r = 0; r < 4; ++r)
        of[(size_t)(mb + 4 * g + r) * Cn + o] = acc[t][r] + bv;
    }
  } else {
    // packed [b][h][row][32dh]
    unsigned short* ot = (unsigned short*)outp;
#pragma unroll
    for (int t = 0; t < 4; ++t) {
      const int o = o0 + 16 * t + c;
      const int h = o >> 5, dh = o & 31;
#pragma unroll
      for (int r = 0; r < 4; ++r) {
        const int m = mb + 4 * g + r;
        const int b = m >> rs, rl = m & ((1 << rs) - 1);
        ot[((size_t)(((b * 8 + h) << rs) + rl)) * 32 + dh] = f2bf(acc[t][r]);
      }
    }
  }
}

// ---------------- fused attention ----------------
// block = 1024 threads (16 waves), wave = (batch, q-quarter); block covers
// (128 q rows, head h). Grid 256 = 1 block/CU -> 4 waves/SIMD TLP at the
// low-traffic geometry (K/V ~128 MB chip-wide; q-quarter waves of one batch
// read identical K/V lines -> L1 dedup). Each wave: 2 q-subtiles per kv-tile.
// rel: 16KB/tile double-buffered LDS (0-conflict swizzle), 3-tile-ahead
// register prefetch (16B/thread); K/V 1-tile-ahead named-register prefetch.
// Issue order per tile: ds_write(S) -> KV(e+1) -> compute -> rel(e+3) last.
__global__ __launch_bounds__(1024, 4) void k_attn(const unsigned short* __restrict__ qt,
                                                  const unsigned short* __restrict__ kt,
                                                  const unsigned short* __restrict__ vt,
                                                  const float* __restrict__ rel,
                                                  unsigned short* __restrict__ ob) {
  __shared__ __align__(16) char s_rel[2][16384];   // 2 x (128 rows x 128B)
  const int tid = threadIdx.x;
  const int lane = tid & 63, w = tid >> 6;
  const int bb = w & 3, qq = w >> 2;               // wave = (batch, q-quarter)
  const int g = lane >> 4, c = lane & 15;
  const int h = blockIdx.x >> 5;                   // 8 heads
  const int q0 = (blockIdx.x & 31) * 128;

  // staging map: row = tid>>3 (0..127), 16B unit su = tid&7 (16B/thread/tile)
  const int srow = tid >> 3, su = tid & 7;
  const float* sgp = rel + ((size_t)h * Nn + q0 + srow) * NKn + su * 4;
  const int swo = srow * 128 + ((su ^ (srow & 7)) << 4);
  char* sb = &s_rel[0][0];

  // Q fragments (B-operand), packed layout -> contiguous loads
  bf16x8 qf[2];
#pragma unroll
  for (int t = 0; t < 2; ++t)
    qf[t] = *(const bf16x8*)(qt + ((size_t)((bb * 8 + h) << 12) + q0 + qq * 32 + 16 * t + c) * 32 + 8 * g);

  bf16x8 ones;
#pragma unroll
  for (int r = 0; r < 8; ++r) ones[r] = (__bf16)1.0f;

  f32x4 acc[2][2] = {};
  f32x4 accl[2] = {};

  const unsigned short* kbase = kt + ((size_t)((bb * 8 + h) << 10)) * 32 + 8 * g;
  const unsigned short* vbase = vt + ((size_t)(bb * 8 + h) * 1024) * 32;

  // one 16x32 sub-tile (t literal from unrolled loop)
  auto sub = [&](const char* rb, int t, bf16x8 k0, bf16x8 k1, bf16x8 v0, bf16x8 v1) {
    f32x4 zero = {};
    f32x4 s0 = __builtin_amdgcn_mfma_f32_16x16x32_bf16(k0, qf[t], zero, 0, 0, 0);
    f32x4 s1 = __builtin_amdgcn_mfma_f32_16x16x32_bf16(k1, qf[t], zero, 0, 0, 0);
    const int rrow = (qq * 32 + 16 * t + c) * 128;
    f32x4 r0 = *(const f32x4*)(rb + rrow + ((g ^ (c & 7)) << 4));
    f32x4 r1 = *(const f32x4*)(rb + rrow + (((4 + g) ^ (c & 7)) << 4));
    s0 += r0 * L2E;
    s1 += r1 * L2E;
    float p0[4], p1[4];
#pragma unroll
    for (int r = 0; r < 4; ++r) {
      p0[r] = __builtin_amdgcn_exp2f(s0[r]);
      p1[r] = __builtin_amdgcn_exp2f(s1[r]);
    }
    u32x4 pw;
    pw[0] = __builtin_amdgcn_perm(__float_as_uint(p0[1]), __float_as_uint(p0[0]), 0x07060302u);
    pw[1] = __builtin_amdgcn_perm(__float_as_uint(p0[3]), __float_as_uint(p0[2]), 0x07060302u);
    pw[2] = __builtin_amdgcn_perm(__float_as_uint(p1[1]), __float_as_uint(p1[0]), 0x07060302u);
    pw[3] = __builtin_amdgcn_perm(__float_as_uint(p1[3]), __float_as_uint(p1[2]), 0x07060302u);
    bf16x8 pf = __builtin_bit_cast(bf16x8, pw);
    accl[t] = __builtin_amdgcn_mfma_f32_16x16x32_bf16(ones, pf, accl[t], 0, 0, 0);
    acc[t][0] = __builtin_amdgcn_mfma_f32_16x16x32_bf16(v0, pf, acc[t][0], 0, 0, 0);
    acc[t][1] = __builtin_amdgcn_mfma_f32_16x16x32_bf16(v1, pf, acc[t][1], 0, 0, 0);
  };

  // per-tile body; rbuf literal at call sites; KV cur/next and S set by reference
  auto tile = [&](int e, int rbuf,
                  bf16x8& k0c, bf16x8& k1c, bf16x8& v0c, bf16x8& v1c,
                  bf16x8& k0n, bf16x8& k1n, bf16x8& v0n, bf16x8& v1n,
                  f32x4& S0) {
    // 1) write rel tile e+1 (regs) into the other LDS buffer
    char* wb = sb + (rbuf ^ 1) * 16384;
    *(f32x4*)(wb + swo) = S0;
    // 2) K/V loads for tile e+1 (oldest in vmcnt queue)
    const int kvn = ((e + 1) & 31) * 32;
    k0n = *(const bf16x8*)(kbase + (size_t)(kvn + c) * 32);
    k1n = *(const bf16x8*)(kbase + (size_t)(kvn + 16 + c) * 32);
    v0n = *(const bf16x8*)(vbase + (size_t)(kvn + c) * 32 + g * 8);
    v1n = *(const bf16x8*)(vbase + (size_t)(kvn + 16 + c) * 32 + g * 8);
    __builtin_amdgcn_sched_barrier(0);
    // 3) compute 2 q-subtiles on current K/V
    const char* rb = sb + rbuf * 16384;
#pragma unroll
    for (int t = 0; t < 2; ++t) sub(rb, t, k0c, k1c, v0c, v1c);
    // 4) rel tile e+3 load LAST (newest; K/V waits never drain it)
    const int rn = ((e + 3) & 31) * 32;
    S0 = *(const f32x4*)(sgp + rn);
  };

  // prologue: rel[0] -> buf0; rel[1] -> SA; rel[2] -> SB; K/V tile0 -> P set
  {
    f32x4 t0 = *(const f32x4*)(sgp);
    *(f32x4*)(sb + swo) = t0;
  }
  f32x4 SA0 = *(const f32x4*)(sgp + 32);
  f32x4 SB0 = *(const f32x4*)(sgp + 64);
  bf16x8 kP0 = *(const bf16x8*)(kbase + (size_t)(c) * 32);
  bf16x8 kP1 = *(const bf16x8*)(kbase + (size_t)(16 + c) * 32);
  bf16x8 vP0 = *(const bf16x8*)(vbase + (size_t)(c) * 32 + g * 8);
  bf16x8 vP1 = *(const bf16x8*)(vbase + (size_t)(16 + c) * 32 + g * 8);
  bf16x8 kQ0, kQ1, vQ0, vQ1;
  __syncthreads();

  for (int ee = 0; ee < 32; ee += 2) {
    tile(ee, 0, kP0, kP1, vP0, vP1, kQ0, kQ1, vQ0, vQ1, SA0);
    __syncthreads();
    tile(ee + 1, 1, kQ0, kQ1, vQ0, vQ1, kP0, kP1, vP0, vP1, SB0);
    __syncthreads();
  }

  // epilogue: divide by l, write attn output bf16 [b, n, h*32 + dv]
#pragma unroll
  for (int t = 0; t < 2; ++t) {
    const float inv = 1.0f / accl[t][0];
#pragma unroll
    for (int hh = 0; hh < 2; ++hh) {
      us4 pk;
      pk[0] = f2bf(acc[t][hh][0] * inv);
      pk[1] = f2bf(acc[t][hh][1] * inv);
      pk[2] = f2bf(acc[t][hh][2] * inv);
      pk[3] = f2bf(acc[t][hh][3] * inv);
      *(us4*)(ob + ((size_t)bb * Nn + q0 + qq * 32 + 16 * t + c) * Cn + h * DHn + hh * 16 + 4 * g) = pk;
    }
  }
}

extern "C" void kernel_launch(void* const* d_in, const int* in_sizes, int n_in,
                              void* d_out, int out_size, void* d_ws, size_t ws_size,
                              hipStream_t stream) {
  const float* x   = (const float*)d_in[0];
  const float* rel = (const float*)d_in[3];
  const float* qw  = (const float*)d_in[4];
  const float* kw  = (const float*)d_in[5];
  const float* vw  = (const float*)d_in[6];
  const float* pw  = (const float*)d_in[7];
  const float* pb  = (const float*)d_in[8];
  const float* srw = (const float*)d_in[9];
  const float* srb = (const float*)d_in[10];
  const float* bng = (const float*)d_in[11];
  const float* bnb = (const float*)d_in[12];
  const float* bnm = (const float*)d_in[13];
  const float* bnv = (const float*)d_in[14];

  char* ws = (char*)d_ws;
  unsigned short* x_bf  = (unsigned short*)(ws + 0);          // 16384x256 bf16 (8 MB)
  unsigned short* q_t   = (unsigned short*)(ws + 8388608);    // [4,8,4096,32] bf16 (8 MB)
  unsigned short* xk_bf = (unsigned short*)(ws + 16777216);   // 4096x256  bf16 (2 MB)
  unsigned short* k_t   = (unsigned short*)(ws + 18874368);   // [4,8,1024,32] bf16 (2 MB)
  unsigned short* v_2   = (unsigned short*)(ws + 20971520);   // [4,8,32,32,32] bf16 (2 MB)
  unsigned short* a_bf  = (unsigned short*)(ws + 23068672);   // 16384x256 bf16 (8 MB)
  unsigned short* w_q   = (unsigned short*)(ws + 31457280);
  unsigned short* w_k   = (unsigned short*)(ws + 31457280 + 131072);
  unsigned short* w_v   = (unsigned short*)(ws + 31457280 + 262144);
  unsigned short* w_p   = (unsigned short*)(ws + 31457280 + 393216);

  // convert inputs to bf16 (q weights pre-scaled by SCALE*L2E)
  k_f32_to_bf16<<<4096, 256, 0, stream>>>(x, x_bf, 1048576, 1.0f);
  k_f32_to_bf16<<<64, 256, 0, stream>>>(qw, w_q, 16384, SCALEc * L2E);
  k_f32_to_bf16<<<64, 256, 0, stream>>>(kw, w_k, 16384, 1.0f);
  k_f32_to_bf16<<<64, 256, 0, stream>>>(vw, w_v, 16384, 1.0f);
  k_f32_to_bf16<<<64, 256, 0, stream>>>(pw, w_p, 16384, 1.0f);

  // spatial reduction + BN
  k_conv_bn<<<dim3(1024, 4), 256, 0, stream>>>(x, srw, srb, bng, bnb, bnm, bnv, xk_bf);

  // projections (LDS-staged GEMMs, 64x64 tiles)
  k_gemm<3><<<dim3(256, 4), 256, 0, stream>>>(x_bf, w_q, (void*)q_t, nullptr, 12);   // Q packed
  k_gemm<3><<<dim3(64, 4), 256, 0, stream>>>(xk_bf, w_k, (void*)k_t, nullptr, 10);   // K packed
  k_gemm<1><<<dim3(64, 4), 256, 0, stream>>>(xk_bf, w_v, (void*)v_2, nullptr, 0);    // V slot-packed

  // fused attention (128-row q-tiles, 1024 threads, 4 waves/SIMD)
  k_attn<<<dim3(256), 1024, 0, stream>>>(q_t, k_t, v_2, rel, a_bf);

  // output projection (f32 + bias) -> d_out
  k_gemm<2><<<dim3(256, 4), 256, 0, stream>>>(a_bf, w_p, d_out, pb, 0);
}

// Round 15
// 72.005 us; speedup vs baseline: 1.1830x; 1.1830x over previous
//
#include <hip/hip_runtime.h>
#include <cstdint>
#include <cstddef>

#define DEV static __device__ __forceinline__

typedef __bf16 bf16x8 __attribute__((ext_vector_type(8)));
typedef __bf16 bf16x4 __attribute__((ext_vector_type(4)));
typedef float  f32x4  __attribute__((ext_vector_type(4)));
typedef unsigned short us4 __attribute__((ext_vector_type(4)));
typedef unsigned short us8 __attribute__((ext_vector_type(8)));
typedef unsigned int   u32x4 __attribute__((ext_vector_type(4)));

DEV unsigned short f2bf(float f) {
  unsigned u = __float_as_uint(f);
  u += 0x7FFFu + ((u >> 16) & 1u);          // round-to-nearest-even
  return (unsigned short)(u >> 16);
}

// fixed problem dims
constexpr int   Bn = 4, Nn = 4096, Cn = 256, HEADSn = 8, DHn = 32, NKn = 1024;
constexpr float SCALEc = 0.17677669529663689f;   // 1/sqrt(32)
constexpr float L2E    = 1.4426950408889634f;

// ---------------- fused weight conversion: qw(scaled), kw, vw, pw in ONE launch ----------------
__global__ void k_cvt_w(const float* __restrict__ qw, const float* __restrict__ kw,
                        const float* __restrict__ vw, const float* __restrict__ pw,
                        unsigned short* __restrict__ wq, unsigned short* __restrict__ wk,
                        unsigned short* __restrict__ wv, unsigned short* __restrict__ wp) {
  const int which = blockIdx.x >> 6;               // 0..3
  const int i = (blockIdx.x & 63) * 256 + threadIdx.x;   // f32x4 unit, 16384 per matrix
  const float* src = which == 0 ? qw : which == 1 ? kw : which == 2 ? vw : pw;
  unsigned short* dst = which == 0 ? wq : which == 1 ? wk : which == 2 ? wv : wp;
  const float scale = which == 0 ? SCALEc * L2E : 1.0f;
  f32x4 v = *(const f32x4*)(src + 4 * (size_t)i);
  us4 o;
  o[0] = f2bf(v[0] * scale); o[1] = f2bf(v[1] * scale);
  o[2] = f2bf(v[2] * scale); o[3] = f2bf(v[3] * scale);
  *(us4*)(dst + 4 * (size_t)i) = o;
}

// ---------------- depthwise 2x2 stride-2 conv + BatchNorm(eval) -> xk bf16 ----------------
__global__ void k_conv_bn(const float* __restrict__ x,
                          const float* __restrict__ srw, const float* __restrict__ srb,
                          const float* __restrict__ bng, const float* __restrict__ bnb,
                          const float* __restrict__ bnm, const float* __restrict__ bnv,
                          unsigned short* __restrict__ xk) {
  const int m = blockIdx.x;           // 0..1023  (i*32+j)
  const int b = blockIdx.y;           // 0..3
  const int c = threadIdx.x;          // 0..255
  const int i = m >> 5, j = m & 31;
  const int n00 = (2 * i) * 64 + 2 * j;
  const size_t base = ((size_t)b * Nn) * Cn + c;
  float w0 = srw[c * 4 + 0], w1 = srw[c * 4 + 1], w2 = srw[c * 4 + 2], w3 = srw[c * 4 + 3];
  float acc = x[base + (size_t)n00 * Cn] * w0
            + x[base + (size_t)(n00 + 1) * Cn] * w1
            + x[base + (size_t)(n00 + 64) * Cn] * w2
            + x[base + (size_t)(n00 + 65) * Cn] * w3
            + srb[c];
  float inv_std = bng[c] * rsqrtf(bnv[c] + 1e-5f);
  acc = (acc - bnm[c]) * inv_std + bnb[c];
  xk[((size_t)b * NKn + m) * Cn + c] = f2bf(acc);
}

// ---------------- LDS-staged bf16 MFMA GEMM: out[m,o] = sum_k A[m,k]*W[o,k] ----------------
// MODE 2: f32 out + bias; MODE 3: [b][h][row][32] packed (rs = log2 rows/batch).
// AF32: A is f32, converted to bf16 during staging (RNE, identical to pre-convert).
template <int MODE, bool AF32>
__global__ __launch_bounds__(256) void k_gemm(const void* __restrict__ Ap,
                                              const unsigned short* __restrict__ W,
                                              void* __restrict__ outp,
                                              const float* __restrict__ bias, int rs) {
  __shared__ __align__(16) unsigned short sA[64 * 256];
  __shared__ __align__(16) unsigned short sW[64 * 256];
  const int tid = threadIdx.x;
  const int lane = tid & 63, w = tid >> 6;
  const int g = lane >> 4, c = lane & 15;
  const int m0 = blockIdx.x * 64, o0 = blockIdx.y * 64;

#pragma unroll
  for (int r = 0; r < 8; ++r) {
    const int row = r * 8 + (tid >> 5);
    const int u = tid & 31;                 // 16B(bf16) unit within row
    const int usw = u ^ (row & 7);
    if (AF32) {
      const float* af = (const float*)Ap;
      f32x4 lo = *(const f32x4*)(af + (size_t)(m0 + row) * Cn + u * 8);
      f32x4 hi = *(const f32x4*)(af + (size_t)(m0 + row) * Cn + u * 8 + 4);
      us8 pk;
      pk[0] = f2bf(lo[0]); pk[1] = f2bf(lo[1]); pk[2] = f2bf(lo[2]); pk[3] = f2bf(lo[3]);
      pk[4] = f2bf(hi[0]); pk[5] = f2bf(hi[1]); pk[6] = f2bf(hi[2]); pk[7] = f2bf(hi[3]);
      *(us8*)(sA + row * Cn + usw * 8) = pk;
    } else {
      const unsigned short* ab = (const unsigned short*)Ap;
      bf16x8 va = *(const bf16x8*)(ab + (size_t)(m0 + row) * Cn + u * 8);
      *(bf16x8*)(sA + row * Cn + usw * 8) = va;
    }
    bf16x8 vw = *(const bf16x8*)(W + (size_t)(o0 + row) * Cn + u * 8);
    *(bf16x8*)(sW + row * Cn + usw * 8) = vw;
  }
  __syncthreads();

  f32x4 acc[4] = {};
  const int rowa = w * 16 + c;
#pragma unroll
  for (int ks = 0; ks < 8; ++ks) {
    bf16x8 af = *(const bf16x8*)(sA + rowa * Cn + ((ks * 4 + g) ^ (c & 7)) * 8);
#pragma unroll
    for (int t = 0; t < 4; ++t) {
      const int roww = 16 * t + c;
      bf16x8 wf = *(const bf16x8*)(sW + roww * Cn + ((ks * 4 + g) ^ (c & 7)) * 8);
      acc[t] = __builtin_amdgcn_mfma_f32_16x16x32_bf16(af, wf, acc[t], 0, 0, 0);
    }
  }

  const int mb = m0 + w * 16;
  if (MODE == 2) {
    float* of = (float*)outp;
#pragma unroll
    for (int t = 0; t < 4; ++t) {
      const int o = o0 + 16 * t + c;
      const float bv = bias[o];
#pragma unroll
      for (int r = 0; r < 4; ++r)
        of[(size_t)(mb + 4 * g + r) * Cn + o] = acc[t][r] + bv;
    }
  } else {
    // packed [b][h][row][32dh]
    unsigned short* ot = (unsigned short*)outp;
#pragma unroll
    for (int t = 0; t < 4; ++t) {
      const int o = o0 + 16 * t + c;
      const int h = o >> 5, dh = o & 31;
#pragma unroll
      for (int r = 0; r < 4; ++r) {
        const int m = mb + 4 * g + r;
        const int b = m >> rs, rl = m & ((1 << rs) - 1);
        ot[((size_t)(((b * 8 + h) << rs) + rl)) * 32 + dh] = f2bf(acc[t][r]);
      }
    }
  }
}

// ---------------- merged K+V projection: stage xk tile once, two outputs ----------------
__global__ __launch_bounds__(256) void k_gemm_kv(const unsigned short* __restrict__ xk,
                                                 const unsigned short* __restrict__ Wk,
                                                 const unsigned short* __restrict__ Wv,
                                                 unsigned short* __restrict__ kt,
                                                 unsigned short* __restrict__ vt) {
  __shared__ __align__(16) unsigned short sA[64 * 256];
  __shared__ __align__(16) unsigned short sWk[64 * 256];
  __shared__ __align__(16) unsigned short sWv[64 * 256];
  const int tid = threadIdx.x;
  const int lane = tid & 63, w = tid >> 6;
  const int g = lane >> 4, c = lane & 15;
  const int m0 = blockIdx.x * 64, o0 = blockIdx.y * 64;

#pragma unroll
  for (int r = 0; r < 8; ++r) {
    const int row = r * 8 + (tid >> 5);
    const int u = tid & 31;
    const int usw = u ^ (row & 7);
    bf16x8 va = *(const bf16x8*)(xk + (size_t)(m0 + row) * Cn + u * 8);
    *(bf16x8*)(sA + row * Cn + usw * 8) = va;
    bf16x8 vk = *(const bf16x8*)(Wk + (size_t)(o0 + row) * Cn + u * 8);
    *(bf16x8*)(sWk + row * Cn + usw * 8) = vk;
    bf16x8 vv = *(const bf16x8*)(Wv + (size_t)(o0 + row) * Cn + u * 8);
    *(bf16x8*)(sWv + row * Cn + usw * 8) = vv;
  }
  __syncthreads();

  f32x4 ak[4] = {}, av[4] = {};
  const int rowa = w * 16 + c;
#pragma unroll
  for (int ks = 0; ks < 8; ++ks) {
    bf16x8 af = *(const bf16x8*)(sA + rowa * Cn + ((ks * 4 + g) ^ (c & 7)) * 8);
#pragma unroll
    for (int t = 0; t < 4; ++t) {
      const int roww = 16 * t + c;
      bf16x8 wkf = *(const bf16x8*)(sWk + roww * Cn + ((ks * 4 + g) ^ (c & 7)) * 8);
      ak[t] = __builtin_amdgcn_mfma_f32_16x16x32_bf16(af, wkf, ak[t], 0, 0, 0);
      bf16x8 wvf = *(const bf16x8*)(sWv + roww * Cn + ((ks * 4 + g) ^ (c & 7)) * 8);
      av[t] = __builtin_amdgcn_mfma_f32_16x16x32_bf16(af, wvf, av[t], 0, 0, 0);
    }
  }

  const int mb = m0 + w * 16;
  // K epilogue: packed [b][h][row][32dh], rows-per-batch 1024
#pragma unroll
  for (int t = 0; t < 4; ++t) {
    const int o = o0 + 16 * t + c;
    const int h = o >> 5, dh = o & 31;
#pragma unroll
    for (int r = 0; r < 4; ++r) {
      const int m = mb + 4 * g + r;
      const int b = m >> 10, rl = m & 1023;
      kt[((size_t)(((b * 8 + h) << 10) + rl)) * 32 + dh] = f2bf(ak[t][r]);
    }
  }
  // V epilogue: slot-packed v2[b][h][kvblk32][dv32][g4][j8]
  {
    const int m4 = mb + 4 * g;
    const int b = m4 >> 10;
    const int kvblk = (m4 & 1023) >> 5;
    const int jh = (m4 >> 4) & 1;
#pragma unroll
    for (int t = 0; t < 4; ++t) {
      const int o = o0 + 16 * t + c;
      const int h = o >> 5, dv = o & 31;
      us4 pk;
      pk[0] = f2bf(av[t][0]); pk[1] = f2bf(av[t][1]);
      pk[2] = f2bf(av[t][2]); pk[3] = f2bf(av[t][3]);
      *(us4*)(vt + ((size_t)(((b * 8 + h) * 32 + kvblk) * 32 + dv)) * 32 + g * 8 + jh * 4) = pk;
    }
  }
}

// ---------------- fused attention (R13 config, unchanged — best measured) ----------------
// block = 512 threads (8 waves), wave = (batch, q-half); block covers
// (128 q rows, head h). Grid 256 = 1 block/CU -> 2 waves/SIMD.
__global__ __launch_bounds__(512, 2) void k_attn(const unsigned short* __restrict__ qt,
                                                 const unsigned short* __restrict__ kt,
                                                 const unsigned short* __restrict__ vt,
                                                 const float* __restrict__ rel,
                                                 unsigned short* __restrict__ ob) {
  __shared__ __align__(16) char s_rel[2][16384];   // 2 x (128 rows x 128B)
  const int tid = threadIdx.x;
  const int lane = tid & 63, w = tid >> 6;
  const int bb = w & 3, qh = w >> 2;               // wave = (batch, q-half)
  const int g = lane >> 4, c = lane & 15;
  const int h = blockIdx.x >> 5;                   // 8 heads
  const int q0 = (blockIdx.x & 31) * 128;

  // staging map: row = tid>>2 (0..127), 2 x 16B units starting at (tid&3)*2
  const int srow = tid >> 2, su2 = (tid & 3) * 2;
  const float* sgp = rel + ((size_t)h * Nn + q0 + srow) * NKn + su2 * 4;
  int swo[2];
#pragma unroll
  for (int j = 0; j < 2; ++j) swo[j] = srow * 128 + (((su2 + j) ^ (srow & 7)) << 4);
  char* sb = &s_rel[0][0];

  // Q fragments (B-operand), packed layout -> contiguous loads
  bf16x8 qf[4];
#pragma unroll
  for (int t = 0; t < 4; ++t)
    qf[t] = *(const bf16x8*)(qt + ((size_t)((bb * 8 + h) << 12) + q0 + qh * 64 + 16 * t + c) * 32 + 8 * g);

  bf16x8 ones;
#pragma unroll
  for (int r = 0; r < 8; ++r) ones[r] = (__bf16)1.0f;

  f32x4 acc[4][2] = {};
  f32x4 accl[4] = {};

  const unsigned short* kbase = kt + ((size_t)((bb * 8 + h) << 10)) * 32 + 8 * g;
  const unsigned short* vbase = vt + ((size_t)(bb * 8 + h) * 1024) * 32;

  // one 16x32 sub-tile (t literal from unrolled loop)
  auto sub = [&](const char* rb, int t, bf16x8 k0, bf16x8 k1, bf16x8 v0, bf16x8 v1) {
    f32x4 zero = {};
    f32x4 s0 = __builtin_amdgcn_mfma_f32_16x16x32_bf16(k0, qf[t], zero, 0, 0, 0);
    f32x4 s1 = __builtin_amdgcn_mfma_f32_16x16x32_bf16(k1, qf[t], zero, 0, 0, 0);
    const int rrow = (qh * 64 + 16 * t + c) * 128;
    f32x4 r0 = *(const f32x4*)(rb + rrow + ((g ^ (c & 7)) << 4));
    f32x4 r1 = *(const f32x4*)(rb + rrow + (((4 + g) ^ (c & 7)) << 4));
    s0 += r0 * L2E;
    s1 += r1 * L2E;
    float p0[4], p1[4];
#pragma unroll
    for (int r = 0; r < 4; ++r) {
      p0[r] = __builtin_amdgcn_exp2f(s0[r]);
      p1[r] = __builtin_amdgcn_exp2f(s1[r]);
    }
    u32x4 pw;
    pw[0] = __builtin_amdgcn_perm(__float_as_uint(p0[1]), __float_as_uint(p0[0]), 0x07060302u);
    pw[1] = __builtin_amdgcn_perm(__float_as_uint(p0[3]), __float_as_uint(p0[2]), 0x07060302u);
    pw[2] = __builtin_amdgcn_perm(__float_as_uint(p1[1]), __float_as_uint(p1[0]), 0x07060302u);
    pw[3] = __builtin_amdgcn_perm(__float_as_uint(p1[3]), __float_as_uint(p1[2]), 0x07060302u);
    bf16x8 pf = __builtin_bit_cast(bf16x8, pw);
    accl[t] = __builtin_amdgcn_mfma_f32_16x16x32_bf16(ones, pf, accl[t], 0, 0, 0);
    acc[t][0] = __builtin_amdgcn_mfma_f32_16x16x32_bf16(v0, pf, acc[t][0], 0, 0, 0);
    acc[t][1] = __builtin_amdgcn_mfma_f32_16x16x32_bf16(v1, pf, acc[t][1], 0, 0, 0);
  };

  // per-tile body; rbuf literal at call sites; KV cur/next and S sets by reference
  auto tile = [&](int e, int rbuf,
                  bf16x8& k0c, bf16x8& k1c, bf16x8& v0c, bf16x8& v1c,
                  bf16x8& k0n, bf16x8& k1n, bf16x8& v0n, bf16x8& v1n,
                  f32x4& S0, f32x4& S1) {
    // 1) write rel tile e+1 (regs) into the other LDS buffer
    char* wb = sb + (rbuf ^ 1) * 16384;
    *(f32x4*)(wb + swo[0]) = S0;
    *(f32x4*)(wb + swo[1]) = S1;
    // 2) K/V loads for tile e+1 (oldest in vmcnt queue)
    const int kvn = ((e + 1) & 31) * 32;
    k0n = *(const bf16x8*)(kbase + (size_t)(kvn + c) * 32);
    k1n = *(const bf16x8*)(kbase + (size_t)(kvn + 16 + c) * 32);
    v0n = *(const bf16x8*)(vbase + (size_t)(kvn + c) * 32 + g * 8);
    v1n = *(const bf16x8*)(vbase + (size_t)(kvn + 16 + c) * 32 + g * 8);
    __builtin_amdgcn_sched_barrier(0);
    // 3) compute 4 q-subtiles on current K/V
    const char* rb = sb + rbuf * 16384;
#pragma unroll
    for (int t = 0; t < 4; ++t) sub(rb, t, k0c, k1c, v0c, v1c);
    // 4) rel tile e+3 loads LAST (newest; K/V waits never drain them)
    const int rn = ((e + 3) & 31) * 32;
    S0 = *(const f32x4*)(sgp + rn);
    S1 = *(const f32x4*)(sgp + rn + 4);
  };

  // prologue: rel[0] -> buf0; rel[1] -> SA; rel[2] -> SB; K/V tile0 -> P set
  {
    f32x4 t0 = *(const f32x4*)(sgp);
    f32x4 t1 = *(const f32x4*)(sgp + 4);
    *(f32x4*)(sb + swo[0]) = t0;
    *(f32x4*)(sb + swo[1]) = t1;
  }
  f32x4 SA0 = *(const f32x4*)(sgp + 32);
  f32x4 SA1 = *(const f32x4*)(sgp + 36);
  f32x4 SB0 = *(const f32x4*)(sgp + 64);
  f32x4 SB1 = *(const f32x4*)(sgp + 68);
  bf16x8 kP0 = *(const bf16x8*)(kbase + (size_t)(c) * 32);
  bf16x8 kP1 = *(const bf16x8*)(kbase + (size_t)(16 + c) * 32);
  bf16x8 vP0 = *(const bf16x8*)(vbase + (size_t)(c) * 32 + g * 8);
  bf16x8 vP1 = *(const bf16x8*)(vbase + (size_t)(16 + c) * 32 + g * 8);
  bf16x8 kQ0, kQ1, vQ0, vQ1;
  __syncthreads();

  for (int ee = 0; ee < 32; ee += 2) {
    tile(ee, 0, kP0, kP1, vP0, vP1, kQ0, kQ1, vQ0, vQ1, SA0, SA1);
    __syncthreads();
    tile(ee + 1, 1, kQ0, kQ1, vQ0, vQ1, kP0, kP1, vP0, vP1, SB0, SB1);
    __syncthreads();
  }

  // epilogue: divide by l, write attn output bf16 [b, n, h*32 + dv]
#pragma unroll
  for (int t = 0; t < 4; ++t) {
    const float inv = 1.0f / accl[t][0];
#pragma unroll
    for (int hh = 0; hh < 2; ++hh) {
      us4 pk;
      pk[0] = f2bf(acc[t][hh][0] * inv);
      pk[1] = f2bf(acc[t][hh][1] * inv);
      pk[2] = f2bf(acc[t][hh][2] * inv);
      pk[3] = f2bf(acc[t][hh][3] * inv);
      *(us4*)(ob + ((size_t)bb * Nn + q0 + qh * 64 + 16 * t + c) * Cn + h * DHn + hh * 16 + 4 * g) = pk;
    }
  }
}

extern "C" void kernel_launch(void* const* d_in, const int* in_sizes, int n_in,
                              void* d_out, int out_size, void* d_ws, size_t ws_size,
                              hipStream_t stream) {
  const float* x   = (const float*)d_in[0];
  const float* rel = (const float*)d_in[3];
  const float* qw  = (const float*)d_in[4];
  const float* kw  = (const float*)d_in[5];
  const float* vw  = (const float*)d_in[6];
  const float* pw  = (const float*)d_in[7];
  const float* pb  = (const float*)d_in[8];
  const float* srw = (const float*)d_in[9];
  const float* srb = (const float*)d_in[10];
  const float* bng = (const float*)d_in[11];
  const float* bnb = (const float*)d_in[12];
  const float* bnm = (const float*)d_in[13];
  const float* bnv = (const float*)d_in[14];

  char* ws = (char*)d_ws;
  unsigned short* q_t   = (unsigned short*)(ws + 0);          // [4,8,4096,32] bf16 (8 MB)
  unsigned short* xk_bf = (unsigned short*)(ws + 8388608);    // 4096x256  bf16 (2 MB)
  unsigned short* k_t   = (unsigned short*)(ws + 10485760);   // [4,8,1024,32] bf16 (2 MB)
  unsigned short* v_2   = (unsigned short*)(ws + 12582912);   // [4,8,32,32,32] bf16 (2 MB)
  unsigned short* a_bf  = (unsigned short*)(ws + 14680064);   // 16384x256 bf16 (8 MB)
  unsigned short* w_q   = (unsigned short*)(ws + 23068672);
  unsigned short* w_k   = (unsigned short*)(ws + 23068672 + 131072);
  unsigned short* w_v   = (unsigned short*)(ws + 23068672 + 262144);
  unsigned short* w_p   = (unsigned short*)(ws + 23068672 + 393216);

  // 1) all weight conversions in one launch (q pre-scaled by SCALE*L2E)
  k_cvt_w<<<256, 256, 0, stream>>>(qw, kw, vw, pw, w_q, w_k, w_v, w_p);

  // 2) spatial reduction + BN
  k_conv_bn<<<dim3(1024, 4), 256, 0, stream>>>(x, srw, srb, bng, bnb, bnm, bnv, xk_bf);

  // 3) Q projection, staging directly from f32 x (in-staging bf16 convert)
  k_gemm<3, true><<<dim3(256, 4), 256, 0, stream>>>((const void*)x, w_q, (void*)q_t, nullptr, 12);

  // 4) merged K+V projections (xk staged once)
  k_gemm_kv<<<dim3(64, 4), 256, 0, stream>>>(xk_bf, w_k, w_v, k_t, v_2);

  // 5) fused attention (R13 config: 128-row q-tiles, 512 threads, 2 waves/SIMD)
  k_attn<<<dim3(256), 512, 0, stream>>>(q_t, k_t, v_2, rel, a_bf);

  // 6) output projection (f32 + bias) -> d_out
  k_gemm<2, false><<<dim3(256, 4), 256, 0, stream>>>((const void*)a_bf, w_p, d_out, pb, 0);
}